// Round 1
// baseline (363.818 us; speedup 1.0000x reference)
//
#include <hip/hip_runtime.h>
#include <stdint.h>

#define NUM_KP 17
#define BATCH  32
#define HDIM   256
#define WDIM   256
#define NCH    (BATCH * NUM_KP)     // 544 channels
#define MAXP   30
#define CAP    8192                 // candidate list capacity (expected ~7300)
#define NBINS  2048
#define BIN_BASE 128001             // (0x3F800000>>13) - (NBINS-1); bins cover ~(0.25,1], lower scores clamp to bin 0
#define TILE   16
#define SLOTS  (TILE + 2)           // 18 rows staged (16 output + 2 halo)
#define RSTRIDE 264                 // 256 data + pads; [3] and [260] are -inf col pads, data at [4..259]

__device__ __forceinline__ unsigned long long shfl_down_u64(unsigned long long v, int off) {
    unsigned lo = (unsigned)v, hi = (unsigned)(v >> 32);
    lo = __shfl_down(lo, off);
    hi = __shfl_down(hi, off);
    return ((unsigned long long)hi << 32) | lo;
}
__device__ __forceinline__ unsigned long long shfl_u64(unsigned long long v, int lane) {
    unsigned lo = (unsigned)v, hi = (unsigned)(v >> 32);
    lo = __shfl(lo, lane);
    hi = __shfl(hi, lane);
    return ((unsigned long long)hi << 32) | lo;
}

__global__ __launch_bounds__(256, 2)
void pose_post_kernel(const float* __restrict__ heat, float* __restrict__ out, int out_size) {
    // LDS budget: 19008 + 32768 + 8192 + 1024 + 2048 + misc ~= 63.1 KB  -> 2 blocks/CU
    __shared__ __align__(16) float rowsL[SLOTS * RSTRIDE];
    __shared__ unsigned s_cand[CAP];          // (bin<<16) | pixel_idx
    __shared__ int s_hist[NBINS];
    __shared__ int s_gsum[NBINS / 8];
    __shared__ unsigned long long s_ref[256]; // exact keys: (score_bits<<32) | ~idx
    __shared__ int s_cnt, s_nref, s_tau;

    const int tid  = threadIdx.x;
    const int chan = blockIdx.x;
    const float* chanptr = heat + (size_t)chan * (HDIM * WDIM);
    const float NEGINF = -__builtin_inff();

    for (int i = tid; i < NBINS; i += 256) s_hist[i] = 0;
    if (tid < SLOTS) {  // column pads, written once (float4 stages never touch them)
        rowsL[tid * RSTRIDE + 3]        = NEGINF;
        rowsL[tid * RSTRIDE + 4 + WDIM] = NEGINF;
    }
    if (tid == 0) { s_cnt = 0; s_nref = 0; }
    __syncthreads();

    // ---- Pass 1: tiled 3x3-NMS, candidate collection + score histogram ----
    for (int tile = 0; tile < HDIM / TILE; ++tile) {
        const int y0 = tile * TILE;
        // stage rows y0-1 .. y0+16 (out-of-range -> -inf), float4 coalesced
        for (int i = tid; i < SLOTS * (WDIM / 4); i += 256) {
            int row = i >> 6;            // 64 float4 per row
            int c   = (i & 63) << 2;
            int gy  = y0 - 1 + row;
            float4 v;
            if (gy >= 0 && gy < HDIM) v = *(const float4*)(chanptr + (gy << 8) + c);
            else                      v = make_float4(NEGINF, NEGINF, NEGINF, NEGINF);
            *(float4*)(&rowsL[row * RSTRIDE + 4 + c]) = v;
        }
        __syncthreads();

        const int t = tid;               // this thread owns column t
        float a0 = rowsL[0 * RSTRIDE + 3 + t];
        float b0 = rowsL[0 * RSTRIDE + 4 + t];
        float c0 = rowsL[0 * RSTRIDE + 5 + t];
        float h0 = fmaxf(a0, fmaxf(b0, c0));
        float a1 = rowsL[1 * RSTRIDE + 3 + t];
        float b1 = rowsL[1 * RSTRIDE + 4 + t];
        float c1 = rowsL[1 * RSTRIDE + 5 + t];
        float h1 = fmaxf(a1, fmaxf(b1, c1));
        float m1 = b1;                   // center value of current output row
        #pragma unroll 4
        for (int r = 1; r <= TILE; ++r) {
            float a = rowsL[(r + 1) * RSTRIDE + 3 + t];
            float b = rowsL[(r + 1) * RSTRIDE + 4 + t];
            float c = rowsL[(r + 1) * RSTRIDE + 5 + t];
            float h2 = fmaxf(a, fmaxf(b, c));
            float v  = m1;
            float hm = fmaxf(h0, fmaxf(h1, h2));  // 3x3 max incl. center
            if (v == hm && v > 0.1f) {
                int idx = ((y0 + r - 1) << 8) | t;
                unsigned bits = __float_as_uint(v);
                int bin = (int)(bits >> 13) - BIN_BASE;
                bin = bin < 0 ? 0 : (bin > NBINS - 1 ? NBINS - 1 : bin);
                int pos = atomicAdd(&s_cnt, 1);
                if (pos < CAP) s_cand[pos] = ((unsigned)bin << 16) | (unsigned)idx;
                atomicAdd(&s_hist[bin], 1);
            }
            h0 = h1; h1 = h2; m1 = b;
        }
        __syncthreads();
    }

    // ---- Pass 2: histogram suffix-scan -> bin threshold tau covering rank MAXP ----
    {
        int s = 0;
        #pragma unroll
        for (int j = 0; j < 8; ++j) s += s_hist[tid * 8 + j];
        s_gsum[tid] = s;
    }
    __syncthreads();
    if (tid == 0) {
        int cum = 0, tau = 0;
        for (int g = NBINS / 8 - 1; g >= 0; --g) {
            int gs = s_gsum[g];
            if (cum + gs >= MAXP) {
                for (int b = g * 8 + 7; b >= g * 8; --b) {
                    cum += s_hist[b];
                    if (cum >= MAXP) { tau = b; break; }
                }
                break;
            }
            cum += gs;
        }
        s_tau = tau;   // stays 0 if total candidates < MAXP -> collect all
    }
    __syncthreads();

    // ---- Pass 3: collect survivors (bin >= tau), re-read exact scores ----
    const int tau   = s_tau;
    const int count = s_cnt < CAP ? s_cnt : CAP;
    for (int i = tid; i < count; i += 256) {
        unsigned p = s_cand[i];
        if ((int)(p >> 16) >= tau) {
            int pos = atomicAdd(&s_nref, 1);
            if (pos < 256) {
                unsigned idx = p & 0xFFFFu;
                float sc = chanptr[idx];
                // key: higher score wins; tie -> smaller idx wins (matches lax.top_k)
                s_ref[pos] = ((unsigned long long)__float_as_uint(sc) << 32) | (unsigned)(~idx);
            }
        }
    }
    __syncthreads();
    const int nref = s_nref < 256 ? s_nref : 256;

    // ---- Pass 4: exact top-30 extraction, wave 0 only (no barriers) ----
    if (tid < 64) {
        unsigned long long k0 = (tid       < nref) ? s_ref[tid]       : 0ull;
        unsigned long long k1 = (tid + 64  < nref) ? s_ref[tid + 64]  : 0ull;
        unsigned long long k2 = (tid + 128 < nref) ? s_ref[tid + 128] : 0ull;
        unsigned long long k3 = (tid + 192 < nref) ? s_ref[tid + 192] : 0ull;
        for (int r = 0; r < MAXP; ++r) {
            unsigned long long best = k0; int bs = 0;
            if (k1 > best) { best = k1; bs = 1; }
            if (k2 > best) { best = k2; bs = 2; }
            if (k3 > best) { best = k3; bs = 3; }
            unsigned long long key = best;
            int slot = (bs << 6) | tid;
            #pragma unroll
            for (int off = 32; off > 0; off >>= 1) {
                unsigned long long ok = shfl_down_u64(key, off);
                int os = __shfl_down(slot, off);
                if (ok > key) { key = ok; slot = os; }
            }
            key  = shfl_u64(key, 0);
            slot = __shfl(slot, 0);
            if ((slot & 63) == tid) {        // I own the winner; remove it
                int which = slot >> 6;
                if      (which == 0) k0 = 0ull;
                else if (which == 1) k1 = 0ull;
                else if (which == 2) k2 = 0ull;
                else                 k3 = 0ull;
            }
            if (tid == 0) {
                float sc, vld; unsigned idx;
                if (key != 0ull) {
                    sc  = __uint_as_float((unsigned)(key >> 32));
                    idx = (~(unsigned)key) & 0xFFFFu;
                    vld = 1.0f;
                } else { sc = NEGINF; idx = 0u; vld = 0.0f; }
                int x = (int)(idx & 255), y = (int)(idx >> 8);
                long long cb = ((long long)chan * MAXP + r) * 2;
                if (cb + 1 < out_size) {
                    out[cb]     = (float)(x * 4);   // coords are (x, y) * STRIDE
                    out[cb + 1] = (float)(y * 4);
                }
                long long so = (long long)NCH * MAXP * 2 + (long long)chan * MAXP + r;
                if (so < out_size) out[so] = sc;
                long long vo = (long long)NCH * MAXP * 3 + (long long)chan * MAXP + r;
                if (vo < out_size) out[vo] = vld;
            }
        }
    }
}

extern "C" void kernel_launch(void* const* d_in, const int* in_sizes, int n_in,
                              void* d_out, int out_size, void* d_ws, size_t ws_size,
                              hipStream_t stream) {
    const float* heat = (const float*)d_in[0];
    float* out = (float*)d_out;
    hipLaunchKernelGGL(pose_post_kernel, dim3(NCH), dim3(256), 0, stream, heat, out, out_size);
}